// Round 2
// baseline (321.919 us; speedup 1.0000x reference)
//
#include <hip/hip_runtime.h>

#define HD __device__ __forceinline__

typedef __attribute__((ext_vector_type(4))) float f32x4;
typedef __attribute__((ext_vector_type(8))) short bf16x8;

constexpr int B_ = 32, S_ = 128, DA = 256, DE = 256, K_ = 12, N_ = 128;
constexpr int W_ = S_ - K_;          // 116
constexpr int BW = B_ * W_;          // 3712 (= 29 * 128)

HD unsigned short f2bf(float f) {
    unsigned u = __float_as_uint(f);
    u += 0x7fffu + ((u >> 16) & 1u);          // round-to-nearest-even
    return (unsigned short)(u >> 16);
}
HD float bf2f(unsigned short h) { return __uint_as_float(((unsigned)h) << 16); }

// ---- kernel 0: detect whether extIdx arrived as int64 (odd 32-bit words all zero) ----
__global__ void k_detect(const unsigned int* __restrict__ idx, unsigned int* __restrict__ flag) {
    __shared__ int anyNZ;
    if (threadIdx.x == 0) anyNZ = 0;
    __syncthreads();
    int nz = 0;
    for (int i = threadIdx.x; i < 4096; i += 256) nz |= (idx[2 * i + 1] != 0u);
    if (nz) atomicOr(&anyNZ, 1);
    __syncthreads();
    if (threadIdx.x == 0) *flag = (anyNZ == 0) ? 1u : 0u;   // 1 => int64
}

// ---- kernel 1: fp32 -> bf16 cast (vectorized) ----
__global__ void k_cast(const float* __restrict__ in, unsigned short* __restrict__ out, int n4) {
    int i = blockIdx.x * 256 + threadIdx.x;
    if (i >= n4) return;
    float4 v = ((const float4*)in)[i];
    ushort4 o;
    o.x = f2bf(v.x); o.y = f2bf(v.y); o.z = f2bf(v.z); o.w = f2bf(v.w);
    ((ushort4*)out)[i] = o;
}

// ---- kernel 2: locC[m][k][e] = sum_a C[m][a] * Wp[k][e][a], bf16 MFMA, 128x128 tile ----
// grid: 12 k * 29 mtiles * 2 etiles = 696 blocks, 256 threads (2x2 waves of 64x64)
__global__ __launch_bounds__(256) void k_locc(const unsigned short* __restrict__ Abf,
                                              const unsigned short* __restrict__ Wpbf,
                                              unsigned short* __restrict__ locC) {
    int bx = blockIdx.x;
    int k  = bx / 58;
    int r  = bx % 58;
    int mt = r >> 1;
    int et = r & 1;

    __shared__ unsigned short As[128][40];   // 32-wide K chunk + 8 pad (bank spread)
    __shared__ unsigned short Bs[128][40];

    int tid  = threadIdx.x;
    int lane = tid & 63;
    int wid  = tid >> 6;
    int wr   = wid >> 1, wc = wid & 1;
    int l15  = lane & 15, lk = lane >> 4;

    f32x4 acc[4][4] = {};

    int srow = tid >> 1, spart = tid & 1;    // 128 rows x 2 half-rows (16 bf16 each)
    int m  = mt * 128 + srow;                // < 3712 always
    int bb = m / W_, ww = m - bb * W_;
    const unsigned short* aSrc = Abf + ((bb * S_ + ww) * DA) + spart * 16;
    const unsigned short* bSrc = Wpbf + ((k * DE + et * 128 + srow) * DA) + spart * 16;

    for (int c = 0; c < 8; ++c) {            // 8 chunks of K=32
        uint4 av0 = ((const uint4*)(aSrc + c * 32))[0];
        uint4 av1 = ((const uint4*)(aSrc + c * 32))[1];
        uint4 bv0 = ((const uint4*)(bSrc + c * 32))[0];
        uint4 bv1 = ((const uint4*)(bSrc + c * 32))[1];
        __syncthreads();                     // previous iteration's reads done
        ((uint4*)&As[srow][spart * 16])[0]     = av0;
        ((uint4*)&As[srow][spart * 16 + 8])[0] = av1;
        ((uint4*)&Bs[srow][spart * 16])[0]     = bv0;
        ((uint4*)&Bs[srow][spart * 16 + 8])[0] = bv1;
        __syncthreads();
        bf16x8 af[4], bfv[4];
        #pragma unroll
        for (int f = 0; f < 4; ++f) {
            af[f]  = *(const bf16x8*)&As[wr * 64 + f * 16 + l15][lk * 8];
            bfv[f] = *(const bf16x8*)&Bs[wc * 64 + f * 16 + l15][lk * 8];
        }
        #pragma unroll
        for (int fi = 0; fi < 4; ++fi)
            #pragma unroll
            for (int fj = 0; fj < 4; ++fj)
                acc[fi][fj] = __builtin_amdgcn_mfma_f32_16x16x32_bf16(af[fi], bfv[fj], acc[fi][fj], 0, 0, 0);
    }

    // epilogue: C/D layout col = lane&15, row = (lane>>4)*4 + reg  [m89/m91 verified]
    #pragma unroll
    for (int fi = 0; fi < 4; ++fi) {
        #pragma unroll
        for (int fj = 0; fj < 4; ++fj) {
            f32x4 v = acc[fi][fj];
            int eOut = et * 128 + wc * 64 + fj * 16 + l15;
            #pragma unroll
            for (int rr = 0; rr < 4; ++rr) {
                int mOut = mt * 128 + wr * 64 + fi * 16 + lk * 4 + rr;
                locC[(mOut * K_ + k) * DE + eOut] = f2bf(v[rr]);
            }
        }
    }
}

// ---- kernel 3: scores + LSE + argmax partials. 2 (b,w) pairs per block, 128 thr each ----
__global__ __launch_bounds__(256) void k_score(const float* __restrict__ E,
                                               const unsigned int* __restrict__ idxRaw,
                                               const unsigned short* __restrict__ locC,
                                               const unsigned int* __restrict__ flag,
                                               float* __restrict__ partial) {
    __shared__ float lcl[2][K_][DE];     // 24 KB
    __shared__ float smat[2][K_][N_];    // 12 KB
    __shared__ float posS[2][K_];

    int tid = threadIdx.x;
    int pl  = tid >> 7;                  // pair-local 0/1
    int t   = tid & 127;                 // thread within pair = neg column
    int p   = blockIdx.x * 2 + pl;       // (b,w) pair index, < 3712
    int b   = p / W_, w = p - b * W_;

    // stage locC (bf16 -> fp32 in LDS)
    const ushort4* src = (const ushort4*)(locC + p * (K_ * DE));
    float* dst = &lcl[pl][0][0];
    for (int i = t; i < (K_ * DE) / 4; i += 128) {
        ushort4 u = src[i];
        dst[4 * i + 0] = bf2f(u.x); dst[4 * i + 1] = bf2f(u.y);
        dst[4 * i + 2] = bf2f(u.z); dst[4 * i + 3] = bf2f(u.w);
    }

    bool i64 = (*flag != 0u);
    int fi = (b * N_ + t) * W_ + w;
    int ridx = i64 ? (int)idxRaw[2 * fi] : (int)idxRaw[fi];

    const float* negRow = E + (size_t)ridx * DE;
    const float* posRow = E + (size_t)(b * S_ + w + t + 1) * DE;   // deref only when t < 12

    float acc[K_];
    #pragma unroll
    for (int k = 0; k < K_; ++k) acc[k] = 0.f;
    float accP = 0.f;

    __syncthreads();

    for (int ec = 0; ec < 8; ++ec) {     // 8 chunks of 32 floats
        float4 rv[8];
        const float4* nr = (const float4*)(negRow + ec * 32);
        #pragma unroll
        for (int i = 0; i < 8; ++i) rv[i] = nr[i];
        #pragma unroll
        for (int k = 0; k < K_; ++k) {
            const float4* lc = (const float4*)&lcl[pl][k][ec * 32];
            float a = acc[k];
            #pragma unroll
            for (int i = 0; i < 8; ++i) {
                float4 cv = lc[i];
                a += rv[i].x * cv.x + rv[i].y * cv.y + rv[i].z * cv.z + rv[i].w * cv.w;
            }
            acc[k] = a;
        }
        if (t < K_) {                    // pos score for k = t
            const float4* pr = (const float4*)(posRow + ec * 32);
            const float4* lc = (const float4*)&lcl[pl][t][ec * 32];
            #pragma unroll
            for (int i = 0; i < 8; ++i) {
                float4 pv = pr[i], cv = lc[i];
                accP += pv.x * cv.x + pv.y * cv.y + pv.z * cv.z + pv.w * cv.w;
            }
        }
    }

    constexpr float inv_e = 1.0f / 256.0f;
    #pragma unroll
    for (int k = 0; k < K_; ++k) smat[pl][k][t] = acc[k] * inv_e;
    if (t < K_) posS[pl][t] = accP * inv_e;
    __syncthreads();

    if (t < 64) {                        // one full wave per pair does the reduction
        for (int k = 0; k < K_; ++k) {
            float v0 = smat[pl][k][t], v1 = smat[pl][k][t + 64];
            float mx = fmaxf(v0, v1);
            #pragma unroll
            for (int off = 32; off > 0; off >>= 1) mx = fmaxf(mx, __shfl_xor(mx, off));
            float ps = posS[pl][k];
            float M  = fmaxf(mx, ps);
            float se = __expf(v0 - M) + __expf(v1 - M);
            #pragma unroll
            for (int off = 32; off > 0; off >>= 1) se += __shfl_xor(se, off);
            se += __expf(ps - M);
            float lse = M + __logf(se);
            if (t == 0) {
                partial[p * 24 + k]      = lse - ps;                 // loss term
                partial[p * 24 + 12 + k] = (ps >= mx) ? 1.0f : 0.0f; // argmax==0
            }
        }
    }
}

// ---- kernel 4: final mean over 3712 pairs, write FLOAT32 outputs (fixed dtype) ----
__global__ void k_reduce(const float* __restrict__ partial, float* __restrict__ out) {
    int o = blockIdx.x;                  // 0..23  (0..11 losses, 12..23 acc)
    float s = 0.f;
    for (int pp = threadIdx.x; pp < BW; pp += 256) s += partial[pp * 24 + o];
    #pragma unroll
    for (int off = 32; off > 0; off >>= 1) s += __shfl_xor(s, off);
    __shared__ float w4[4];
    if ((threadIdx.x & 63) == 0) w4[threadIdx.x >> 6] = s;
    __syncthreads();
    if (threadIdx.x == 0)
        out[o] = (w4[0] + w4[1] + w4[2] + w4[3]) * (1.0f / BW);
}

extern "C" void kernel_launch(void* const* d_in, const int* in_sizes, int n_in,
                              void* d_out, int out_size, void* d_ws, size_t ws_size,
                              hipStream_t stream) {
    const float* cFeat = (const float*)d_in[0];
    const float* E     = (const float*)d_in[1];
    const float* Wp    = (const float*)d_in[2];
    const unsigned int* idxRaw = (const unsigned int*)d_in[3];

    char* ws = (char*)d_ws;
    unsigned short* locC    = (unsigned short*)(ws);             // 3712*12*256*2 = 22,806,528 B
    unsigned short* Abf     = (unsigned short*)(ws + 22806528);  // 2,097,152 B
    unsigned short* Wpbf    = (unsigned short*)(ws + 24903680);  // 1,572,864 B
    float*          partial = (float*)        (ws + 26476544);   // 3712*24*4 = 356,352 B
    unsigned int*   flag    = (unsigned int*) (ws + 26832896);   // 4 B

    k_detect<<<1, 256, 0, stream>>>(idxRaw, flag);
    k_cast<<<(B_ * S_ * DA / 4 + 255) / 256, 256, 0, stream>>>(cFeat, Abf, B_ * S_ * DA / 4);
    k_cast<<<(K_ * DE * DA / 4 + 255) / 256, 256, 0, stream>>>(Wp, Wpbf, K_ * DE * DA / 4);
    k_locc<<<12 * 58, 256, 0, stream>>>(Abf, Wpbf, locC);
    k_score<<<BW / 2, 256, 0, stream>>>(E, idxRaw, locC, flag, partial);
    k_reduce<<<24, 256, 0, stream>>>(partial, (float*)d_out);
}

// Round 3
// 137.303 us; speedup vs baseline: 2.3446x; 2.3446x over previous
//
#include <hip/hip_runtime.h>

#define HD __device__ __forceinline__

typedef __attribute__((ext_vector_type(4))) float f32x4;
typedef __attribute__((ext_vector_type(8))) short bf16x8;

constexpr int B_ = 32, S_ = 128, DA = 256, DE = 256, K_ = 12, N_ = 128;
constexpr int W_ = S_ - K_;          // 116
constexpr int BW = B_ * W_;          // 3712 (= 29 * 128)
constexpr int NC = 144;              // 128 neg cols + 16 pos-pad cols

HD unsigned short f2bf(float f) {
    unsigned u = __float_as_uint(f);
    u += 0x7fffu + ((u >> 16) & 1u);          // round-to-nearest-even
    return (unsigned short)(u >> 16);
}
HD float bf2f(unsigned short h) { return __uint_as_float(((unsigned)h) << 16); }

// ---- kernel 0: detect whether extIdx arrived as int64 (odd 32-bit words all zero) ----
__global__ void k_detect(const unsigned int* __restrict__ idx, unsigned int* __restrict__ flag) {
    __shared__ int anyNZ;
    if (threadIdx.x == 0) anyNZ = 0;
    __syncthreads();
    int nz = 0;
    for (int i = threadIdx.x; i < 4096; i += 256) nz |= (idx[2 * i + 1] != 0u);
    if (nz) atomicOr(&anyNZ, 1);
    __syncthreads();
    if (threadIdx.x == 0) *flag = (anyNZ == 0) ? 1u : 0u;   // 1 => int64
}

// ---- kernel 1: fp32 -> bf16 cast (vectorized) ----
__global__ void k_cast(const float* __restrict__ in, unsigned short* __restrict__ out, int n4) {
    int i = blockIdx.x * 256 + threadIdx.x;
    if (i >= n4) return;
    float4 v = ((const float4*)in)[i];
    ushort4 o;
    o.x = f2bf(v.x); o.y = f2bf(v.y); o.z = f2bf(v.z); o.w = f2bf(v.w);
    ((ushort4*)out)[i] = o;
}

// ---- kernel 2: locC[m][k][e] = sum_a C[m][a] * Wp[k][e][a], bf16 MFMA, 128x128 tile ----
__global__ __launch_bounds__(256) void k_locc(const unsigned short* __restrict__ Abf,
                                              const unsigned short* __restrict__ Wpbf,
                                              unsigned short* __restrict__ locC) {
    int bx = blockIdx.x;
    int k  = bx / 58;
    int r  = bx % 58;
    int mt = r >> 1;
    int et = r & 1;

    __shared__ unsigned short As[128][40];
    __shared__ unsigned short Bs[128][40];

    int tid  = threadIdx.x;
    int lane = tid & 63;
    int wid  = tid >> 6;
    int wr   = wid >> 1, wc = wid & 1;
    int l15  = lane & 15, lk = lane >> 4;

    f32x4 acc[4][4] = {};

    int srow = tid >> 1, spart = tid & 1;
    int m  = mt * 128 + srow;
    int bb = m / W_, ww = m - bb * W_;
    const unsigned short* aSrc = Abf + ((bb * S_ + ww) * DA) + spart * 16;
    const unsigned short* bSrc = Wpbf + ((k * DE + et * 128 + srow) * DA) + spart * 16;

    for (int c = 0; c < 8; ++c) {
        uint4 av0 = ((const uint4*)(aSrc + c * 32))[0];
        uint4 av1 = ((const uint4*)(aSrc + c * 32))[1];
        uint4 bv0 = ((const uint4*)(bSrc + c * 32))[0];
        uint4 bv1 = ((const uint4*)(bSrc + c * 32))[1];
        __syncthreads();
        ((uint4*)&As[srow][spart * 16])[0]     = av0;
        ((uint4*)&As[srow][spart * 16 + 8])[0] = av1;
        ((uint4*)&Bs[srow][spart * 16])[0]     = bv0;
        ((uint4*)&Bs[srow][spart * 16 + 8])[0] = bv1;
        __syncthreads();
        bf16x8 af[4], bfv[4];
        #pragma unroll
        for (int f = 0; f < 4; ++f) {
            af[f]  = *(const bf16x8*)&As[wr * 64 + f * 16 + l15][lk * 8];
            bfv[f] = *(const bf16x8*)&Bs[wc * 64 + f * 16 + l15][lk * 8];
        }
        #pragma unroll
        for (int fi = 0; fi < 4; ++fi)
            #pragma unroll
            for (int fj = 0; fj < 4; ++fj)
                acc[fi][fj] = __builtin_amdgcn_mfma_f32_16x16x32_bf16(af[fi], bfv[fj], acc[fi][fj], 0, 0, 0);
    }

    #pragma unroll
    for (int fi = 0; fi < 4; ++fi) {
        #pragma unroll
        for (int fj = 0; fj < 4; ++fj) {
            f32x4 v = acc[fi][fj];
            int eOut = et * 128 + wc * 64 + fj * 16 + l15;
            #pragma unroll
            for (int rr = 0; rr < 4; ++rr) {
                int mOut = mt * 128 + wr * 64 + fi * 16 + lk * 4 + rr;
                locC[(mOut * K_ + k) * DE + eOut] = f2bf(v[rr]);
            }
        }
    }
}

// ---- kernel 3: MFMA score + LSE. One block (4 waves) per (b,w) pair. ----
// S[k][t] = (1/e) * sum_e locC[p][k][e] * Ebf[row(t)][e]; cols 0..127 = negs,
// col 128+k = pos for k. M-dim = k (12 used of 16), N-dim = t, K-dim = e.
__global__ __launch_bounds__(256) void k_score(const unsigned short* __restrict__ Ebf,
                                               const unsigned int* __restrict__ idxRaw,
                                               const unsigned short* __restrict__ locC,
                                               const unsigned int* __restrict__ flag,
                                               float* __restrict__ partial) {
    __shared__ float smat[K_][NC + 4];   // ~7.1 KB

    int tid  = threadIdx.x;
    int lane = tid & 63;
    int wid  = tid >> 6;
    int l15  = lane & 15, lk = lane >> 4;
    int p    = blockIdx.x;               // pair index < 3712
    int b    = p / W_, w = p - b * W_;

    bool i64 = (*flag != 0u);

    // A fragments: locC[p][k=l15][e], zero rows k>=12. 8 k-steps of 32.
    bf16x8 af[8];
    const unsigned short* aBase = locC + ((size_t)p * K_ + l15) * DE + lk * 8;
    #pragma unroll
    for (int ks = 0; ks < 8; ++ks) {
        bf16x8 a = {};
        if (l15 < K_) a = *(const bf16x8*)(aBase + ks * 32);
        af[ks] = a;
    }

    // wave nf assignment: wave0: {0,4,8}, wave1: {1,5}, wave2: {2,6}, wave3: {3,7}
    int nnf = (wid == 0) ? 3 : 2;
    int nfl[3] = { wid, wid + 4, 8 };

    constexpr float inv_e = 1.0f / 256.0f;

    for (int q = 0; q < nnf; ++q) {
        int nf  = nfl[q];
        int row = nf * 16 + l15;         // logical column (t) this lane feeds
        int erow;
        if (row < N_) {
            int fi = (b * N_ + row) * W_ + w;
            erow = i64 ? (int)idxRaw[2 * fi] : (int)idxRaw[fi];
        } else {
            int j = row - N_;
            erow = b * S_ + ((j < K_) ? (w + j + 1) : 0);
        }
        const unsigned short* bBase = Ebf + (size_t)erow * DE + lk * 8;

        f32x4 acc = {};
        #pragma unroll
        for (int ks = 0; ks < 8; ++ks) {
            bf16x8 bfv = *(const bf16x8*)(bBase + ks * 32);
            acc = __builtin_amdgcn_mfma_f32_16x16x32_bf16(af[ks], bfv, acc, 0, 0, 0);
        }
        // D layout: col = lane&15 (t), row = lk*4+reg (k). Keep k<12 (lk<3).
        if (lk < 3) {
            #pragma unroll
            for (int rr = 0; rr < 4; ++rr)
                smat[lk * 4 + rr][nf * 16 + l15] = acc[rr] * inv_e;
        }
    }
    __syncthreads();

    // LSE + argmax: wave w handles k = 3w .. 3w+2
    for (int kk = 0; kk < 3; ++kk) {
        int k = wid * 3 + kk;
        float v0 = smat[k][lane], v1 = smat[k][lane + 64];
        float mx = fmaxf(v0, v1);
        #pragma unroll
        for (int off = 32; off > 0; off >>= 1) mx = fmaxf(mx, __shfl_xor(mx, off));
        float ps = smat[k][N_ + k];
        float M  = fmaxf(mx, ps);
        float se = __expf(v0 - M) + __expf(v1 - M);
        #pragma unroll
        for (int off = 32; off > 0; off >>= 1) se += __shfl_xor(se, off);
        se += __expf(ps - M);
        if (lane == 0) {
            partial[p * 24 + k]      = M + __logf(se) - ps;       // loss term
            partial[p * 24 + 12 + k] = (ps >= mx) ? 1.0f : 0.0f;  // argmax==0
        }
    }
}

// ---- kernel 4: final mean over 3712 pairs, float32 outputs ----
__global__ void k_reduce(const float* __restrict__ partial, float* __restrict__ out) {
    int o = blockIdx.x;                  // 0..23
    float s = 0.f;
    for (int pp = threadIdx.x; pp < BW; pp += 256) s += partial[pp * 24 + o];
    #pragma unroll
    for (int off = 32; off > 0; off >>= 1) s += __shfl_xor(s, off);
    __shared__ float w4[4];
    if ((threadIdx.x & 63) == 0) w4[threadIdx.x >> 6] = s;
    __syncthreads();
    if (threadIdx.x == 0)
        out[o] = (w4[0] + w4[1] + w4[2] + w4[3]) * (1.0f / BW);
}

extern "C" void kernel_launch(void* const* d_in, const int* in_sizes, int n_in,
                              void* d_out, int out_size, void* d_ws, size_t ws_size,
                              hipStream_t stream) {
    const float* cFeat = (const float*)d_in[0];
    const float* E     = (const float*)d_in[1];
    const float* Wp    = (const float*)d_in[2];
    const unsigned int* idxRaw = (const unsigned int*)d_in[3];

    char* ws = (char*)d_ws;
    unsigned short* locC    = (unsigned short*)(ws);             // 22,806,528 B
    unsigned short* Abf     = (unsigned short*)(ws + 22806528);  //  2,097,152 B
    unsigned short* Wpbf    = (unsigned short*)(ws + 24903680);  //  1,572,864 B
    float*          partial = (float*)        (ws + 26476544);   //    356,352 B
    unsigned int*   flag    = (unsigned int*) (ws + 26832896);   //        128 B
    unsigned short* Ebf     = (unsigned short*)(ws + 26833024);  //  2,097,152 B

    k_detect<<<1, 256, 0, stream>>>(idxRaw, flag);
    k_cast<<<(B_ * S_ * DA / 4 + 255) / 256, 256, 0, stream>>>(cFeat, Abf, B_ * S_ * DA / 4);
    k_cast<<<(K_ * DE * DA / 4 + 255) / 256, 256, 0, stream>>>(Wp, Wpbf, K_ * DE * DA / 4);
    k_cast<<<(B_ * S_ * DE / 4 + 255) / 256, 256, 0, stream>>>(E, Ebf, B_ * S_ * DE / 4);
    k_locc<<<12 * 58, 256, 0, stream>>>(Abf, Wpbf, locC);
    k_score<<<BW, 256, 0, stream>>>(Ebf, idxRaw, locC, flag, partial);
    k_reduce<<<24, 256, 0, stream>>>(partial, (float*)d_out);
}

// Round 4
// 126.735 us; speedup vs baseline: 2.5401x; 1.0834x over previous
//
#include <hip/hip_runtime.h>

#define HD __device__ __forceinline__

typedef __attribute__((ext_vector_type(4))) float f32x4;
typedef __attribute__((ext_vector_type(8))) short bf16x8;

constexpr int B_ = 32, S_ = 128, DA = 256, DE = 256, K_ = 12, N_ = 128;
constexpr int W_ = S_ - K_;          // 116
constexpr int BW = B_ * W_;          // 3712 (= 29 * 128)

HD unsigned short f2bf(float f) {
    unsigned u = __float_as_uint(f);
    u += 0x7fffu + ((u >> 16) & 1u);          // round-to-nearest-even
    return (unsigned short)(u >> 16);
}

// ---- kernel 0: fused casts (A, Wp, E) + int64 detect, split by blockIdx ----
__global__ void k_prep(const float* __restrict__ A, const float* __restrict__ Wp,
                       const float* __restrict__ E, const unsigned int* __restrict__ idx,
                       unsigned short* __restrict__ Abf, unsigned short* __restrict__ Wpbf,
                       unsigned short* __restrict__ Ebf, unsigned int* __restrict__ flag) {
    int bx = blockIdx.x;
    const float* src; unsigned short* dst; int base;
    if (bx < 1024)      { src = A;  dst = Abf;  base = bx; }
    else if (bx < 1792) { src = Wp; dst = Wpbf; base = bx - 1024; }
    else if (bx < 2816) { src = E;  dst = Ebf;  base = bx - 1792; }
    else {
        __shared__ int anyNZ;
        if (threadIdx.x == 0) anyNZ = 0;
        __syncthreads();
        int nz = 0;
        for (int i = threadIdx.x; i < 4096; i += 256) nz |= (idx[2 * i + 1] != 0u);
        if (nz) atomicOr(&anyNZ, 1);
        __syncthreads();
        if (threadIdx.x == 0) *flag = (anyNZ == 0) ? 1u : 0u;   // 1 => int64
        return;
    }
    int i = base * 256 + threadIdx.x;
    float4 v = ((const float4*)src)[i];
    ushort4 o;
    o.x = f2bf(v.x); o.y = f2bf(v.y); o.z = f2bf(v.z); o.w = f2bf(v.w);
    ((ushort4*)dst)[i] = o;
}

// ---- kernel 2: locC[m][k][e] = sum_a C[m][a] * Wp[k][e][a], bf16 MFMA, 128x128 tile ----
__global__ __launch_bounds__(256) void k_locc(const unsigned short* __restrict__ Abf,
                                              const unsigned short* __restrict__ Wpbf,
                                              unsigned short* __restrict__ locC) {
    int bx = blockIdx.x;
    int k  = bx / 58;
    int r  = bx % 58;
    int mt = r >> 1;
    int et = r & 1;

    __shared__ unsigned short As[128][40];
    __shared__ unsigned short Bs[128][40];

    int tid  = threadIdx.x;
    int lane = tid & 63;
    int wid  = tid >> 6;
    int wr   = wid >> 1, wc = wid & 1;
    int l15  = lane & 15, lk = lane >> 4;

    f32x4 acc[4][4] = {};

    int srow = tid >> 1, spart = tid & 1;
    int m  = mt * 128 + srow;
    int bb = m / W_, ww = m - bb * W_;
    const unsigned short* aSrc = Abf + ((bb * S_ + ww) * DA) + spart * 16;
    const unsigned short* bSrc = Wpbf + ((k * DE + et * 128 + srow) * DA) + spart * 16;

    for (int c = 0; c < 8; ++c) {
        uint4 av0 = ((const uint4*)(aSrc + c * 32))[0];
        uint4 av1 = ((const uint4*)(aSrc + c * 32))[1];
        uint4 bv0 = ((const uint4*)(bSrc + c * 32))[0];
        uint4 bv1 = ((const uint4*)(bSrc + c * 32))[1];
        __syncthreads();
        ((uint4*)&As[srow][spart * 16])[0]     = av0;
        ((uint4*)&As[srow][spart * 16 + 8])[0] = av1;
        ((uint4*)&Bs[srow][spart * 16])[0]     = bv0;
        ((uint4*)&Bs[srow][spart * 16 + 8])[0] = bv1;
        __syncthreads();
        bf16x8 af[4], bfv[4];
        #pragma unroll
        for (int f = 0; f < 4; ++f) {
            af[f]  = *(const bf16x8*)&As[wr * 64 + f * 16 + l15][lk * 8];
            bfv[f] = *(const bf16x8*)&Bs[wc * 64 + f * 16 + l15][lk * 8];
        }
        #pragma unroll
        for (int fi = 0; fi < 4; ++fi)
            #pragma unroll
            for (int fj = 0; fj < 4; ++fj)
                acc[fi][fj] = __builtin_amdgcn_mfma_f32_16x16x32_bf16(af[fi], bfv[fj], acc[fi][fj], 0, 0, 0);
    }

    #pragma unroll
    for (int fi = 0; fi < 4; ++fi) {
        #pragma unroll
        for (int fj = 0; fj < 4; ++fj) {
            f32x4 v = acc[fi][fj];
            int eOut = et * 128 + wc * 64 + fj * 16 + l15;
            #pragma unroll
            for (int rr = 0; rr < 4; ++rr) {
                int mOut = mt * 128 + wr * 64 + fi * 16 + lk * 4 + rr;
                locC[(mOut * K_ + k) * DE + eOut] = f2bf(v[rr]);
            }
        }
    }
}

// ---- kernel 3: MFMA score + in-register LSE. Wave = one (b,w) pair, 4 pairs/block ----
// S[k][col] = (1/e) * sum_e locC[p][k][e] * Ebf[row(col)][e]; cols 0..127 negs,
// col 128+k = pos for k. D layout: col = lane&15, row(k) = (lane>>4)*4 + reg.
__global__ __launch_bounds__(256) void k_score(const unsigned short* __restrict__ Ebf,
                                               const unsigned int* __restrict__ idxRaw,
                                               const unsigned short* __restrict__ locC,
                                               const unsigned int* __restrict__ flag,
                                               float* __restrict__ partial) {
    int tid  = threadIdx.x;
    int lane = tid & 63;
    int wid  = tid >> 6;
    int l15  = lane & 15, lk = lane >> 4;
    int p    = blockIdx.x * 4 + wid;     // pair index < 3712
    int b    = p / W_, w = p - b * W_;

    bool i64 = (*flag != 0u);

    // gather rows for all 9 col-groups (independent loads, issued upfront)
    int rows[9];
    #pragma unroll
    for (int nf = 0; nf < 9; ++nf) {
        int col = nf * 16 + l15;
        if (col < N_) {
            int fi = (b * N_ + col) * W_ + w;
            rows[nf] = i64 ? (int)idxRaw[2 * fi] : (int)idxRaw[fi];
        } else {
            int j = col - N_;
            rows[nf] = b * S_ + ((j < K_) ? (w + j + 1) : 0);
        }
    }

    // A fragments: locC[p][k=l15][e], rows k>=12 zeroed
    bf16x8 af[8];
    const unsigned short* aBase = locC + ((size_t)p * K_ + l15) * DE + lk * 8;
    #pragma unroll
    for (int ks = 0; ks < 8; ++ks) {
        bf16x8 a = {};
        if (l15 < K_) a = *(const bf16x8*)(aBase + ks * 32);
        af[ks] = a;
    }

    f32x4 accs[9];
    #pragma unroll
    for (int nf = 0; nf < 9; ++nf) {
        const unsigned short* bBase = Ebf + (size_t)rows[nf] * DE + lk * 8;
        f32x4 acc = {};
        #pragma unroll
        for (int ks = 0; ks < 8; ++ks) {
            bf16x8 bfv = *(const bf16x8*)(bBase + ks * 32);
            acc = __builtin_amdgcn_mfma_f32_16x16x32_bf16(af[ks], bfv, acc, 0, 0, 0);
        }
        accs[nf] = acc;
    }

    constexpr float inv_e = 1.0f / 256.0f;

    // raw-max over the 8 neg groups (this lane's col slice), then 16-lane col-reduce
    float m0[4], s0[4];
    #pragma unroll
    for (int rr = 0; rr < 4; ++rr) {
        float mx = accs[0][rr];
        #pragma unroll
        for (int nf = 1; nf < 8; ++nf) mx = fmaxf(mx, accs[nf][rr]);
        m0[rr] = mx;
    }
    #pragma unroll
    for (int off = 1; off < 16; off <<= 1)
        #pragma unroll
        for (int rr = 0; rr < 4; ++rr) m0[rr] = fmaxf(m0[rr], __shfl_xor(m0[rr], off));

    #pragma unroll
    for (int rr = 0; rr < 4; ++rr) {
        float s = 0.f;
        #pragma unroll
        for (int nf = 0; nf < 8; ++nf) s += __expf((accs[nf][rr] - m0[rr]) * inv_e);
        s0[rr] = s;
    }
    #pragma unroll
    for (int off = 1; off < 16; off <<= 1)
        #pragma unroll
        for (int rr = 0; rr < 4; ++rr) s0[rr] += __shfl_xor(s0[rr], off);

    // lanes with l15 = k (<12) and lk = k>>2 hold pos score in accs[8][k&3]
    if (l15 < K_ && lk == (l15 >> 2)) {
        int k = l15;
        #pragma unroll
        for (int rr = 0; rr < 4; ++rr) {
            if ((k & 3) == rr) {
                float ps   = accs[8][rr] * inv_e;
                float mneg = m0[rr] * inv_e;
                float M    = fmaxf(mneg, ps);
                float tot  = s0[rr] * __expf(mneg - M) + __expf(ps - M);
                partial[k * BW + p]        = M + __logf(tot) - ps;       // loss term
                partial[(12 + k) * BW + p] = (ps >= mneg) ? 1.0f : 0.0f; // argmax==0
            }
        }
    }
}

// ---- kernel 4: final mean over 3712 pairs, float32 outputs ----
__global__ void k_reduce(const float* __restrict__ partial, float* __restrict__ out) {
    int o = blockIdx.x;                  // 0..23
    float s = 0.f;
    for (int i = threadIdx.x; i < BW; i += 256) s += partial[o * BW + i];
    #pragma unroll
    for (int off = 32; off > 0; off >>= 1) s += __shfl_xor(s, off);
    __shared__ float w4[4];
    if ((threadIdx.x & 63) == 0) w4[threadIdx.x >> 6] = s;
    __syncthreads();
    if (threadIdx.x == 0)
        out[o] = (w4[0] + w4[1] + w4[2] + w4[3]) * (1.0f / BW);
}

extern "C" void kernel_launch(void* const* d_in, const int* in_sizes, int n_in,
                              void* d_out, int out_size, void* d_ws, size_t ws_size,
                              hipStream_t stream) {
    const float* cFeat = (const float*)d_in[0];
    const float* E     = (const float*)d_in[1];
    const float* Wp    = (const float*)d_in[2];
    const unsigned int* idxRaw = (const unsigned int*)d_in[3];

    char* ws = (char*)d_ws;
    unsigned short* locC    = (unsigned short*)(ws);             // 22,806,528 B
    unsigned short* Abf     = (unsigned short*)(ws + 22806528);  //  2,097,152 B
    unsigned short* Wpbf    = (unsigned short*)(ws + 24903680);  //  1,572,864 B
    float*          partial = (float*)        (ws + 26476544);   //    356,352 B
    unsigned int*   flag    = (unsigned int*) (ws + 26832896);   //        128 B
    unsigned short* Ebf     = (unsigned short*)(ws + 26833024);  //  2,097,152 B

    k_prep<<<2817, 256, 0, stream>>>(cFeat, Wp, E, idxRaw, Abf, Wpbf, Ebf, flag);
    k_locc<<<12 * 58, 256, 0, stream>>>(Abf, Wpbf, locC);
    k_score<<<BW / 4, 256, 0, stream>>>(Ebf, idxRaw, locC, flag, partial);
    k_reduce<<<24, 256, 0, stream>>>(partial, (float*)d_out);
}